// Round 1
// baseline (281.670 us; speedup 1.0000x reference)
//
#include <hip/hip_runtime.h>

#define NN 8192
#define FIN 512
#define FOUT 256

typedef _Float16 f16;
typedef __attribute__((ext_vector_type(8))) _Float16 f16x8;
typedef __attribute__((ext_vector_type(4))) _Float16 f16x4;
typedef __attribute__((ext_vector_type(4))) float f32x4;
typedef __attribute__((ext_vector_type(4))) int i32x4;

__device__ __forceinline__ float lrelu(float x) { return fmaxf(x, 0.2f * x); }

// ---- prep h: f32 -> f16 hi/lo split (for accurate split-f16 GEMM)
__global__ void k_prep_h(const float* __restrict__ h, f16* __restrict__ hh,
                         f16* __restrict__ hl) {
  int idx = (blockIdx.x * 256 + threadIdx.x) * 4;
  f32x4 v = *(const f32x4*)(h + idx);
  f16x4 hi, lo;
#pragma unroll
  for (int i = 0; i < 4; ++i) {
    f16 a = (f16)v[i];
    hi[i] = a;
    lo[i] = (f16)(v[i] - (float)a);
  }
  *(f16x4*)(hh + idx) = hi;
  *(f16x4*)(hl + idx) = lo;
}

// ---- prep W: f32 [FIN][FOUT] -> f16 hi/lo transposed [FOUT][FIN]
__global__ void k_prep_w(const float* __restrict__ W, f16* __restrict__ wth,
                         f16* __restrict__ wtl) {
  int id = blockIdx.x * 256 + threadIdx.x;  // 131072 total
  int c = id >> 9, k = id & 511;
  float v = W[k * FOUT + c];
  f16 a = (f16)v;
  wth[c * FIN + k] = a;
  wtl[c * FIN + k] = (f16)(v - (float)a);
}

// ---- GEMM1: Wh = h @ W via split-f16 MFMA. Emits WhT (f16, [FOUT][NN]),
// Wh1 = Wh@a1, Wh2 = Wh@a2 (f32). Tile: 32 rows x 256 cols, 4 waves.
__launch_bounds__(256, 2)
__global__ void k_gemm1(const f16* __restrict__ hh, const f16* __restrict__ hl,
                        const f16* __restrict__ wth, const f16* __restrict__ wtl,
                        const float* __restrict__ avec, f16* __restrict__ whT,
                        float* __restrict__ wh1, float* __restrict__ wh2) {
  int i0 = blockIdx.x * 32;
  int tid = threadIdx.x;
  int w = tid >> 6, l = tid & 63, m = l & 15, g = l >> 4;
  f32x4 acc[2][4] = {};
#pragma unroll 1
  for (int k0 = 0; k0 < FIN; k0 += 32) {
    f16x8 ah[2], al[2], bh[4], bl[4];
#pragma unroll
    for (int rf = 0; rf < 2; ++rf) {
      int ro = (i0 + 16 * rf + m) * FIN + k0 + 8 * g;
      ah[rf] = *(const f16x8*)(hh + ro);
      al[rf] = *(const f16x8*)(hl + ro);
    }
#pragma unroll
    for (int cf = 0; cf < 4; ++cf) {
      int co = (64 * w + 16 * cf + m) * FIN + k0 + 8 * g;
      bh[cf] = *(const f16x8*)(wth + co);
      bl[cf] = *(const f16x8*)(wtl + co);
    }
#pragma unroll
    for (int rf = 0; rf < 2; ++rf)
#pragma unroll
      for (int cf = 0; cf < 4; ++cf) {
        acc[rf][cf] = __builtin_amdgcn_mfma_f32_16x16x32_f16(ah[rf], bh[cf], acc[rf][cf], 0, 0, 0);
        acc[rf][cf] = __builtin_amdgcn_mfma_f32_16x16x32_f16(ah[rf], bl[cf], acc[rf][cf], 0, 0, 0);
        acc[rf][cf] = __builtin_amdgcn_mfma_f32_16x16x32_f16(al[rf], bh[cf], acc[rf][cf], 0, 0, 0);
      }
  }
  __shared__ float tile[32][FOUT + 1];
#pragma unroll
  for (int rf = 0; rf < 2; ++rf)
#pragma unroll
    for (int cf = 0; cf < 4; ++cf)
#pragma unroll
      for (int r = 0; r < 4; ++r)
        tile[16 * rf + 4 * g + r][64 * w + 16 * cf + m] = acc[rf][cf][r];
  __syncthreads();
  {  // WhT: one thread per column, 32 rows contiguous
    int c = tid;
    f16x8 vv[4];
#pragma unroll
    for (int r = 0; r < 32; ++r) vv[r >> 3][r & 7] = (f16)tile[r][c];
#pragma unroll
    for (int q = 0; q < 4; ++q) *(f16x8*)(whT + c * NN + i0 + 8 * q) = vv[q];
  }
  {  // Wh1/Wh2 row dots: 8 lanes per row
    int r = tid >> 3, ls = tid & 7;
    float s1 = 0.f, s2 = 0.f;
    for (int c = ls; c < FOUT; c += 8) {
      float v = tile[r][c];
      s1 = fmaf(v, avec[c], s1);
      s2 = fmaf(v, avec[FOUT + c], s2);
    }
#pragma unroll
    for (int off = 1; off < 8; off <<= 1) {
      s1 += __shfl_xor(s1, off);
      s2 += __shfl_xor(s2, off);
    }
    if (ls == 0) {
      wh1[i0 + r] = s1;
      wh2[i0 + r] = s2;
    }
  }
}

// ---- global max of Wh2 (safe softmax shift bound)
__global__ void k_max2(const float* __restrict__ wh2, float* __restrict__ m2) {
  int t = threadIdx.x;
  float mx = -1e30f;
  for (int i = t; i < NN; i += 256) mx = fmaxf(mx, wh2[i]);
#pragma unroll
  for (int off = 1; off < 64; off <<= 1) mx = fmaxf(mx, __shfl_xor(mx, off));
  __shared__ float sm[4];
  if ((t & 63) == 0) sm[t >> 6] = mx;
  __syncthreads();
  if (t == 0) m2[0] = fmaxf(fmaxf(sm[0], sm[1]), fmaxf(sm[2], sm[3]));
}

// ---- fused masked-softmax + PV. Grid: (NN/32 row-blocks) x 2 j-splits.
// Per block: 32 rows x 4096 j. Per 128-k group: all 4 waves generate the
// swizzled LDS P tile (f16), then each wave does 32 MFMAs on its 64 cols.
__launch_bounds__(256, 2)
__global__ void k_attn(const int* __restrict__ adj, const f16* __restrict__ whT,
                       const float* __restrict__ wh1, const float* __restrict__ wh2,
                       const float* __restrict__ m2g, float* __restrict__ accP,
                       float* __restrict__ zP) {
  int bx = blockIdx.x;
  int js = bx & 1, rb = bx >> 1;
  int i0 = rb * 32;
  int jbase = js * 4096;
  int tid = threadIdx.x, w = tid >> 6, l = tid & 63, m = l & 15, g = l >> 4;
  int rloc = 16 * (w & 1) + m;  // row this lane generates
  int kh = w >> 1;              // k-half within each 32-step
  float M2 = m2g[0];
  float w1 = wh1[i0 + rloc];
  float mrow = lrelu(w1 + M2);
  f32x4 acc[2][4] = {};
  float zacc = 0.f;
  __shared__ f16 P[32 * 128];  // [32 rows][128 k], 16B-granule XOR swizzle
  char* Pb = (char*)P;
  const int* adjrow = adj + (i0 + rloc) * NN;
  int koff = 16 * kh + 4 * g;

  i32x4 av[4];
  f32x4 w2v[4];
#pragma unroll
  for (int s = 0; s < 4; ++s) {
    av[s] = *(const i32x4*)(adjrow + jbase + 32 * s + koff);
    w2v[s] = *(const f32x4*)(wh2 + jbase + 32 * s + koff);
  }
#pragma unroll 1
  for (int grp = 0; grp < 32; ++grp) {
    int j0 = jbase + grp * 128;
    // prefetch next group's adj + wh2 (latency hidden under gen+MFMA)
    i32x4 avn[4];
    f32x4 w2n[4];
    int jn = jbase + (grp < 31 ? (grp + 1) * 128 : grp * 128);
#pragma unroll
    for (int s = 0; s < 4; ++s) {
      avn[s] = *(const i32x4*)(adjrow + jn + 32 * s + koff);
      w2n[s] = *(const f32x4*)(wh2 + jn + 32 * s + koff);
    }
    // generate P
#pragma unroll
    for (int s = 0; s < 4; ++s) {
      f16x4 pk;
      float zp = 0.f;
#pragma unroll
      for (int e = 0; e < 4; ++e) {
        float sc = lrelu(w1 + w2v[s][e]);
        float p = (av[s][e] > 0) ? __expf(sc - mrow) : 0.f;
        zp += p;
        pk[e] = (f16)p;
      }
      zacc += zp;
      int q = 4 * s + 2 * kh + (g >> 1);
      int sw = q ^ (rloc & 7);
      *(f16x4*)(Pb + rloc * 256 + sw * 16 + (g & 1) * 8) = pk;
    }
    __syncthreads();
    // MFMA phase: per sub-step, A from LDS, B from WhT (L2-resident)
#pragma unroll
    for (int s = 0; s < 4; ++s) {
      f16x8 afr[2];
#pragma unroll
      for (int rf = 0; rf < 2; ++rf) {
        int r = 16 * rf + m;
        int q = 4 * s + g;
        afr[rf] = *(const f16x8*)(Pb + r * 256 + (q ^ (r & 7)) * 16);
      }
#pragma unroll
      for (int cf = 0; cf < 4; ++cf) {
        int c = 64 * w + 16 * cf + m;
        f16x8 bfr = *(const f16x8*)(whT + c * NN + j0 + 32 * s + 8 * g);
        acc[0][cf] = __builtin_amdgcn_mfma_f32_16x16x32_f16(afr[0], bfr, acc[0][cf], 0, 0, 0);
        acc[1][cf] = __builtin_amdgcn_mfma_f32_16x16x32_f16(afr[1], bfr, acc[1][cf], 0, 0, 0);
      }
    }
#pragma unroll
    for (int s = 0; s < 4; ++s) {
      av[s] = avn[s];
      w2v[s] = w2n[s];
    }
    __syncthreads();
  }
  // Z: sum lane partials over the 4 lane-groups, then across wave pairs
  zacc += __shfl_xor(zacc, 16);
  zacc += __shfl_xor(zacc, 32);
  __shared__ float zbuf[4][16];
  if (l < 16) zbuf[w][l] = zacc;
  __syncthreads();
  if (tid < 32) {
    int hi = tid >> 4;
    float z = zbuf[hi][tid & 15] + zbuf[hi + 2][tid & 15];
    zP[js * NN + i0 + tid] = z;
  }
  // partial accumulator out (f32)
  float* ap = accP + (size_t)js * NN * FOUT;
#pragma unroll
  for (int rf = 0; rf < 2; ++rf)
#pragma unroll
    for (int cf = 0; cf < 4; ++cf)
#pragma unroll
      for (int r = 0; r < 4; ++r)
        ap[(i0 + 16 * rf + 4 * g + r) * FOUT + 64 * w + 16 * cf + m] = acc[rf][cf][r];
}

// ---- combine partials, divide by Z, elu
__global__ void k_combine(const float* __restrict__ accP, const float* __restrict__ zP,
                          float* __restrict__ out) {
  int id = blockIdx.x * 256 + threadIdx.x;
  int idx = id * 4;
  int row = idx >> 8;
  f32x4 a0 = *(const f32x4*)(accP + idx);
  f32x4 a1 = *(const f32x4*)(accP + NN * FOUT + idx);
  float z = zP[row] + zP[NN + row];
  float inv = (z > 0.f) ? 1.f / z : 0.f;
  f32x4 o;
#pragma unroll
  for (int i = 0; i < 4; ++i) {
    float x = (a0[i] + a1[i]) * inv;
    o[i] = (x > 0.f) ? x : expm1f(x);
  }
  *(f32x4*)(out + idx) = o;
}

extern "C" void kernel_launch(void* const* d_in, const int* in_sizes, int n_in,
                              void* d_out, int out_size, void* d_ws, size_t ws_size,
                              hipStream_t stream) {
  const float* h = (const float*)d_in[0];
  const int* adj = (const int*)d_in[1];
  const float* W = (const float*)d_in[2];
  const float* a = (const float*)d_in[3];
  (void)in_sizes; (void)n_in; (void)out_size; (void)ws_size;

  char* ws = (char*)d_ws;
  size_t off = 0;
  auto alloc = [&](size_t bytes) {
    void* p = ws + off;
    off = (off + bytes + 255) & ~(size_t)255;
    return p;
  };
  f16* hh = (f16*)alloc((size_t)NN * FIN * 2);
  f16* hl = (f16*)alloc((size_t)NN * FIN * 2);
  f16* wth = (f16*)alloc((size_t)FOUT * FIN * 2);
  f16* wtl = (f16*)alloc((size_t)FOUT * FIN * 2);
  f16* whT = (f16*)alloc((size_t)FOUT * NN * 2);
  float* wh1 = (float*)alloc((size_t)NN * 4);
  float* wh2 = (float*)alloc((size_t)NN * 4);
  float* m2 = (float*)alloc(256);
  float* accP = (float*)alloc((size_t)2 * NN * FOUT * 4);
  float* zP = (float*)alloc((size_t)2 * NN * 4);

  k_prep_h<<<NN * FIN / 1024, 256, 0, stream>>>(h, hh, hl);
  k_prep_w<<<FIN * FOUT / 256, 256, 0, stream>>>(W, wth, wtl);
  k_gemm1<<<NN / 32, 256, 0, stream>>>(hh, hl, wth, wtl, a, whT, wh1, wh2);
  k_max2<<<1, 256, 0, stream>>>(wh2, m2);
  k_attn<<<(NN / 32) * 2, 256, 0, stream>>>(adj, whT, wh1, wh2, m2, accP, zP);
  k_combine<<<NN * FOUT / 1024, 256, 0, stream>>>(accP, zP, (float*)d_out);
}

// Round 2
// 251.901 us; speedup vs baseline: 1.1182x; 1.1182x over previous
//
#include <hip/hip_runtime.h>

#define NN 8192
#define FIN 512
#define FOUT 256
#define JS 8
#define STRIP (NN / JS)  // 1024 j per split

typedef _Float16 f16;
typedef __attribute__((ext_vector_type(8))) _Float16 f16x8;
typedef __attribute__((ext_vector_type(4))) _Float16 f16x4;
typedef __attribute__((ext_vector_type(4))) float f32x4;
typedef __attribute__((ext_vector_type(4))) int i32x4;

__device__ __forceinline__ float lrelu(float x) { return fmaxf(x, 0.2f * x); }

// ---- prep h: f32 -> f16 hi/lo split (for accurate split-f16 GEMM)
__global__ void k_prep_h(const float* __restrict__ h, f16* __restrict__ hh,
                         f16* __restrict__ hl) {
  int idx = (blockIdx.x * 256 + threadIdx.x) * 4;
  f32x4 v = *(const f32x4*)(h + idx);
  f16x4 hi, lo;
#pragma unroll
  for (int i = 0; i < 4; ++i) {
    f16 a = (f16)v[i];
    hi[i] = a;
    lo[i] = (f16)(v[i] - (float)a);
  }
  *(f16x4*)(hh + idx) = hi;
  *(f16x4*)(hl + idx) = lo;
}

// ---- prep W: f32 [FIN][FOUT] -> f16 hi/lo transposed [FOUT][FIN]
__global__ void k_prep_w(const float* __restrict__ W, f16* __restrict__ wth,
                         f16* __restrict__ wtl) {
  int id = blockIdx.x * 256 + threadIdx.x;  // 131072 total
  int c = id >> 9, k = id & 511;
  float v = W[k * FOUT + c];
  f16 a = (f16)v;
  wth[c * FIN + k] = a;
  wtl[c * FIN + k] = (f16)(v - (float)a);
}

// ---- GEMM1: Wh = h @ W via split-f16 MFMA. Emits WhT (f16, [FOUT][NN]),
// Wh1 = Wh@a1, Wh2 = Wh@a2 (f32). Tile: 32 rows x 256 cols, 4 waves.
__launch_bounds__(256, 2)
__global__ void k_gemm1(const f16* __restrict__ hh, const f16* __restrict__ hl,
                        const f16* __restrict__ wth, const f16* __restrict__ wtl,
                        const float* __restrict__ avec, f16* __restrict__ whT,
                        float* __restrict__ wh1, float* __restrict__ wh2) {
  int i0 = blockIdx.x * 32;
  int tid = threadIdx.x;
  int w = tid >> 6, l = tid & 63, m = l & 15, g = l >> 4;
  f32x4 acc[2][4] = {};
#pragma unroll 1
  for (int k0 = 0; k0 < FIN; k0 += 32) {
    f16x8 ah[2], al[2], bh[4], bl[4];
#pragma unroll
    for (int rf = 0; rf < 2; ++rf) {
      int ro = (i0 + 16 * rf + m) * FIN + k0 + 8 * g;
      ah[rf] = *(const f16x8*)(hh + ro);
      al[rf] = *(const f16x8*)(hl + ro);
    }
#pragma unroll
    for (int cf = 0; cf < 4; ++cf) {
      int co = (64 * w + 16 * cf + m) * FIN + k0 + 8 * g;
      bh[cf] = *(const f16x8*)(wth + co);
      bl[cf] = *(const f16x8*)(wtl + co);
    }
#pragma unroll
    for (int rf = 0; rf < 2; ++rf)
#pragma unroll
      for (int cf = 0; cf < 4; ++cf) {
        acc[rf][cf] = __builtin_amdgcn_mfma_f32_16x16x32_f16(ah[rf], bh[cf], acc[rf][cf], 0, 0, 0);
        acc[rf][cf] = __builtin_amdgcn_mfma_f32_16x16x32_f16(ah[rf], bl[cf], acc[rf][cf], 0, 0, 0);
        acc[rf][cf] = __builtin_amdgcn_mfma_f32_16x16x32_f16(al[rf], bh[cf], acc[rf][cf], 0, 0, 0);
      }
  }
  __shared__ float tile[32][FOUT + 1];
#pragma unroll
  for (int rf = 0; rf < 2; ++rf)
#pragma unroll
    for (int cf = 0; cf < 4; ++cf)
#pragma unroll
      for (int r = 0; r < 4; ++r)
        tile[16 * rf + 4 * g + r][64 * w + 16 * cf + m] = acc[rf][cf][r];
  __syncthreads();
  {  // WhT: one thread per column, 32 rows contiguous
    int c = tid;
    f16x8 vv[4];
#pragma unroll
    for (int r = 0; r < 32; ++r) vv[r >> 3][r & 7] = (f16)tile[r][c];
#pragma unroll
    for (int q = 0; q < 4; ++q) *(f16x8*)(whT + c * NN + i0 + 8 * q) = vv[q];
  }
  {  // Wh1/Wh2 row dots: 8 lanes per row
    int r = tid >> 3, ls = tid & 7;
    float s1 = 0.f, s2 = 0.f;
    for (int c = ls; c < FOUT; c += 8) {
      float v = tile[r][c];
      s1 = fmaf(v, avec[c], s1);
      s2 = fmaf(v, avec[FOUT + c], s2);
    }
#pragma unroll
    for (int off = 1; off < 8; off <<= 1) {
      s1 += __shfl_xor(s1, off);
      s2 += __shfl_xor(s2, off);
    }
    if (ls == 0) {
      wh1[i0 + r] = s1;
      wh2[i0 + r] = s2;
    }
  }
}

// ---- global max of Wh2 (safe softmax shift bound)
__global__ void k_max2(const float* __restrict__ wh2, float* __restrict__ m2) {
  int t = threadIdx.x;
  float mx = -1e30f;
  for (int i = t; i < NN; i += 256) mx = fmaxf(mx, wh2[i]);
#pragma unroll
  for (int off = 1; off < 64; off <<= 1) mx = fmaxf(mx, __shfl_xor(mx, off));
  __shared__ float sm[4];
  if ((t & 63) == 0) sm[t >> 6] = mx;
  __syncthreads();
  if (t == 0) m2[0] = fmaxf(fmaxf(sm[0], sm[1]), fmaxf(sm[2], sm[3]));
}

// ---- fused masked-softmax + PV, barrier-free, P generated in-register.
// Grid: (NN/128 row-blocks) x JS j-splits. Each wave owns 32 rows x STRIP j
// and all 256 output cols. Lane l generates its own A-fragment:
// A[l&15][8*(l>>4)+e] = P[row][j], no LDS needed.
__launch_bounds__(256, 2)
__global__ void k_attn(const int* __restrict__ adj, const f16* __restrict__ whT,
                       const float* __restrict__ wh1, const float* __restrict__ wh2,
                       const float* __restrict__ m2g, float* __restrict__ accP,
                       float* __restrict__ zP) {
  int bx = blockIdx.x;
  int js = bx & (JS - 1), rb = bx >> 3;
  int tid = threadIdx.x, w = tid >> 6, l = tid & 63, m = l & 15, g = l >> 4;
  int i0 = rb * 128 + w * 32;
  int jbase = js * STRIP;
  float M2 = m2g[0];
  float w1r0 = wh1[i0 + m], w1r1 = wh1[i0 + 16 + m];
  float mrow0 = lrelu(w1r0 + M2), mrow1 = lrelu(w1r1 + M2);
  f32x4 acc[2][16] = {};
  float zacc0 = 0.f, zacc1 = 0.f;
  const int* ar0 = adj + (size_t)(i0 + m) * NN + jbase + 8 * g;
  const int* ar1 = ar0 + (size_t)16 * NN;
  const float* w2p = wh2 + jbase + 8 * g;
  const f16* bp = whT + (size_t)m * NN + jbase + 8 * g;

  i32x4 a0a = __builtin_nontemporal_load((const i32x4*)ar0);
  i32x4 a0b = __builtin_nontemporal_load((const i32x4*)(ar0 + 4));
  i32x4 a1a = __builtin_nontemporal_load((const i32x4*)ar1);
  i32x4 a1b = __builtin_nontemporal_load((const i32x4*)(ar1 + 4));
  f32x4 wva = *(const f32x4*)w2p;
  f32x4 wvb = *(const f32x4*)(w2p + 4);

#pragma unroll 1
  for (int t = 0; t < STRIP / 32; ++t) {
    int nxt = (t < STRIP / 32 - 1) ? (t + 1) * 32 : t * 32;
    // prefetch next k-step (latency hides under exp + MFMA below)
    i32x4 n0a = __builtin_nontemporal_load((const i32x4*)(ar0 + nxt));
    i32x4 n0b = __builtin_nontemporal_load((const i32x4*)(ar0 + nxt + 4));
    i32x4 n1a = __builtin_nontemporal_load((const i32x4*)(ar1 + nxt));
    i32x4 n1b = __builtin_nontemporal_load((const i32x4*)(ar1 + nxt + 4));
    f32x4 nwa = *(const f32x4*)(w2p + nxt);
    f32x4 nwb = *(const f32x4*)(w2p + nxt + 4);

    // generate A-fragments in-register
    f16x8 afr0, afr1;
#pragma unroll
    for (int e = 0; e < 4; ++e) {
      float sca = lrelu(w1r0 + wva[e]);
      float p0a = (a0a[e] > 0) ? __expf(sca - mrow0) : 0.f;
      float scb = lrelu(w1r0 + wvb[e]);
      float p0b = (a0b[e] > 0) ? __expf(scb - mrow0) : 0.f;
      float sc1a = lrelu(w1r1 + wva[e]);
      float p1a = (a1a[e] > 0) ? __expf(sc1a - mrow1) : 0.f;
      float sc1b = lrelu(w1r1 + wvb[e]);
      float p1b = (a1b[e] > 0) ? __expf(sc1b - mrow1) : 0.f;
      zacc0 += p0a + p0b;
      zacc1 += p1a + p1b;
      afr0[e] = (f16)p0a;
      afr0[4 + e] = (f16)p0b;
      afr1[e] = (f16)p1a;
      afr1[4 + e] = (f16)p1b;
    }

    // B from whT (L2/L3-resident) + MFMA; 32 independent accumulators
    const f16* bt = bp + t * 32;
#pragma unroll
    for (int cf = 0; cf < 16; ++cf) {
      f16x8 bfr = *(const f16x8*)(bt + (size_t)cf * 16 * NN);
      acc[0][cf] = __builtin_amdgcn_mfma_f32_16x16x32_f16(afr0, bfr, acc[0][cf], 0, 0, 0);
      acc[1][cf] = __builtin_amdgcn_mfma_f32_16x16x32_f16(afr1, bfr, acc[1][cf], 0, 0, 0);
    }
    a0a = n0a; a0b = n0b; a1a = n1a; a1b = n1b;
    wva = nwa; wvb = nwb;
  }

  // Z: reduce the 4 duplicate lane-groups (bits 4,5 of lane id)
  zacc0 += __shfl_xor(zacc0, 16);
  zacc0 += __shfl_xor(zacc0, 32);
  zacc1 += __shfl_xor(zacc1, 16);
  zacc1 += __shfl_xor(zacc1, 32);
  if (l < 16) {
    zP[(size_t)js * NN + i0 + m] = zacc0;
    zP[(size_t)js * NN + i0 + 16 + m] = zacc1;
  }
  // partial accumulator out (f32, nontemporal: written once, read once)
  float* ap = accP + (size_t)js * NN * FOUT;
#pragma unroll
  for (int rf = 0; rf < 2; ++rf)
#pragma unroll
    for (int cf = 0; cf < 16; ++cf)
#pragma unroll
      for (int r = 0; r < 4; ++r)
        __builtin_nontemporal_store(
            acc[rf][cf][r],
            ap + (size_t)(i0 + 16 * rf + 4 * g + r) * FOUT + 16 * cf + m);
}

// ---- combine JS partials, divide by Z, elu
__global__ void k_combine(const float* __restrict__ accP, const float* __restrict__ zP,
                          float* __restrict__ out) {
  int id = blockIdx.x * 256 + threadIdx.x;
  size_t idx = (size_t)id * 4;
  int row = (int)(idx >> 8);
  f32x4 s = {};
#pragma unroll
  for (int p = 0; p < JS; ++p) {
    f32x4 v = __builtin_nontemporal_load((const f32x4*)(accP + (size_t)p * NN * FOUT + idx));
    s[0] += v[0]; s[1] += v[1]; s[2] += v[2]; s[3] += v[3];
  }
  float z = 0.f;
#pragma unroll
  for (int p = 0; p < JS; ++p) z += zP[(size_t)p * NN + row];
  float inv = (z > 0.f) ? 1.f / z : 0.f;
  f32x4 o;
#pragma unroll
  for (int i = 0; i < 4; ++i) {
    float x = s[i] * inv;
    o[i] = (x > 0.f) ? x : expm1f(x);
  }
  *(f32x4*)(out + idx) = o;
}

extern "C" void kernel_launch(void* const* d_in, const int* in_sizes, int n_in,
                              void* d_out, int out_size, void* d_ws, size_t ws_size,
                              hipStream_t stream) {
  const float* h = (const float*)d_in[0];
  const int* adj = (const int*)d_in[1];
  const float* W = (const float*)d_in[2];
  const float* a = (const float*)d_in[3];
  (void)in_sizes; (void)n_in; (void)out_size; (void)ws_size;

  char* ws = (char*)d_ws;
  size_t off = 0;
  auto alloc = [&](size_t bytes) {
    void* p = ws + off;
    off = (off + bytes + 255) & ~(size_t)255;
    return p;
  };
  // accP is only written by k_attn (after gemm1 is done with the prep
  // buffers), so hh/hl/wth/wtl alias the front of the accP region.
  float* accP = (float*)alloc((size_t)JS * NN * FOUT * 4);  // 64 MB
  f16* whT = (f16*)alloc((size_t)FOUT * NN * 2);
  float* wh1 = (float*)alloc((size_t)NN * 4);
  float* wh2 = (float*)alloc((size_t)NN * 4);
  float* m2 = (float*)alloc(256);
  float* zP = (float*)alloc((size_t)JS * NN * 4);
  // aliased prep buffers (lifetime ends when k_gemm1 completes)
  char* pb = (char*)accP;
  f16* hh = (f16*)pb;
  f16* hl = (f16*)(pb + (size_t)NN * FIN * 2);
  f16* wth = (f16*)(pb + (size_t)NN * FIN * 4);
  f16* wtl = (f16*)(pb + (size_t)NN * FIN * 4 + (size_t)FOUT * FIN * 2);

  k_prep_h<<<NN * FIN / 1024, 256, 0, stream>>>(h, hh, hl);
  k_prep_w<<<FIN * FOUT / 256, 256, 0, stream>>>(W, wth, wtl);
  k_gemm1<<<NN / 32, 256, 0, stream>>>(hh, hl, wth, wtl, a, whT, wh1, wh2);
  k_max2<<<1, 256, 0, stream>>>(wh2, m2);
  k_attn<<<(NN / 128) * JS, 256, 0, stream>>>(adj, whT, wh1, wh2, m2, accP, zP);
  k_combine<<<NN * FOUT / 1024, 256, 0, stream>>>(accP, zP, (float*)d_out);
}